// Round 2
// baseline (3224.145 us; speedup 1.0000x reference)
//
#include <hip/hip_runtime.h>

#define NN 50000
#define NR 4
#define NE 800000
#define DD 128

// ---------------------------------------------------------------------------
// rel_w = softmax(features @ Wrw + brw)   [NN, 4]
// one wave per node; lane owns 2 feature dims; butterfly reduce 4 dots.
// ---------------------------------------------------------------------------
__global__ __launch_bounds__(256) void relw_kernel(
    const float* __restrict__ feat, const float* __restrict__ Wrw,
    const float* __restrict__ brw, float* __restrict__ relw) {
  int wave = threadIdx.x >> 6, lane = threadIdx.x & 63;
  int n = blockIdx.x * 4 + wave;
  if (n >= NN) return;
  float2 f = reinterpret_cast<const float2*>(feat + (size_t)n * DD)[lane];
  // Wrw is [128][4] row-major: each row is exactly one float4
  float4 w0 = reinterpret_cast<const float4*>(Wrw)[2 * lane];
  float4 w1 = reinterpret_cast<const float4*>(Wrw)[2 * lane + 1];
  float a0 = f.x * w0.x + f.y * w1.x;
  float a1 = f.x * w0.y + f.y * w1.y;
  float a2 = f.x * w0.z + f.y * w1.z;
  float a3 = f.x * w0.w + f.y * w1.w;
  for (int off = 32; off; off >>= 1) {
    a0 += __shfl_xor(a0, off);
    a1 += __shfl_xor(a1, off);
    a2 += __shfl_xor(a2, off);
    a3 += __shfl_xor(a3, off);
  }
  if (lane == 0) {
    a0 += brw[0]; a1 += brw[1]; a2 += brw[2]; a3 += brw[3];
    float m = fmaxf(fmaxf(a0, a1), fmaxf(a2, a3));
    float e0 = __expf(a0 - m), e1 = __expf(a1 - m);
    float e2 = __expf(a2 - m), e3 = __expf(a3 - m);
    float inv = 1.f / (e0 + e1 + e2 + e3);
    reinterpret_cast<float4*>(relw)[n] =
        make_float4(e0 * inv, e1 * inv, e2 * inv, e3 * inv);
  }
}

// ---------------------------------------------------------------------------
// Scatter pass for relation r:
//   H[dst]  += w_e * features[src]   (128 f32 per edge, atomics)
//   S[r][dst] += w_e
// one wave per edge; lane owns 2 dims (float2).
// NOTE: harness delivers edge_index as INT32 ([4][2][NE]), not int64.
// ---------------------------------------------------------------------------
__global__ __launch_bounds__(256) void scatter_kernel(
    const float* __restrict__ feat, const int* __restrict__ eidx,
    const float* __restrict__ ew, float* __restrict__ H,
    float* __restrict__ S, int r) {
  int wave = threadIdx.x >> 6, lane = threadIdx.x & 63;
  int e = blockIdx.x * 4 + wave;
  if (e >= NE) return;
  const int* ei = eidx + (size_t)r * 2 * NE;
  int src = ei[e];
  int dst = ei[NE + e];
  float w = ew[(size_t)r * NE + e];
  float2 f = reinterpret_cast<const float2*>(feat + (size_t)src * DD)[lane];
  float* Hrow = H + (size_t)dst * DD;
  // native global_atomic_add_f32 (default atomicAdd(float*) may CAS-loop)
  unsafeAtomicAdd(Hrow + 2 * lane, w * f.x);
  unsafeAtomicAdd(Hrow + 2 * lane + 1, w * f.y);
  if (lane == 0) unsafeAtomicAdd(S + (size_t)r * NN + dst, w);
}

// ---------------------------------------------------------------------------
// combined += rel_w[:,r] * (H @ Wr[r] + S_r * br[r])
// block = 256 thr, 32 nodes/block (4 sub-iters of 8). Wr[r] (64KB) in LDS,
// H rows staged in LDS. thread: node nl = t>>5, 4 outs at dgrp = t&31.
// FIRST pass writes (out is poisoned), later passes accumulate.
// ---------------------------------------------------------------------------
template <bool FIRST>
__global__ __launch_bounds__(256) void combine_kernel(
    const float* __restrict__ H, const float* __restrict__ S,
    const float* __restrict__ relw, const float* __restrict__ Wr,
    const float* __restrict__ br, float* __restrict__ out, int r) {
  __shared__ float wlds[DD * DD];   // 64 KB
  __shared__ float hlds[8][DD];     // 4 KB
  const float* W = Wr + (size_t)r * DD * DD;
  for (int i = threadIdx.x; i < DD * DD / 4; i += 256)
    reinterpret_cast<float4*>(wlds)[i] = reinterpret_cast<const float4*>(W)[i];
  int dgrp = threadIdx.x & 31, nl = threadIdx.x >> 5;
  float4 bv = reinterpret_cast<const float4*>(br + (size_t)r * DD)[dgrp];
  int nbase = blockIdx.x * 32;
  for (int s = 0; s < 4; ++s) {
    int n0 = nbase + s * 8;
    __syncthreads();
    {  // stage 8 H rows (same (nl,dgrp) indexing as compute)
      int n = n0 + nl;
      float4 hv = make_float4(0.f, 0.f, 0.f, 0.f);
      if (n < NN) hv = reinterpret_cast<const float4*>(H + (size_t)n * DD)[dgrp];
      reinterpret_cast<float4*>(&hlds[nl][0])[dgrp] = hv;
    }
    __syncthreads();
    int n = n0 + nl;
    float sv = 0.f, rw = 0.f;
    if (n < NN) {
      sv = S[(size_t)r * NN + n];
      rw = relw[n * 4 + r];
    }
    float4 acc = make_float4(sv * bv.x, sv * bv.y, sv * bv.z, sv * bv.w);
#pragma unroll 8
    for (int k = 0; k < DD; ++k) {
      float h = hlds[nl][k];
      float4 wv = reinterpret_cast<const float4*>(&wlds[k * DD])[dgrp];
      acc.x += h * wv.x; acc.y += h * wv.y;
      acc.z += h * wv.z; acc.w += h * wv.w;
    }
    if (n < NN) {
      float4* op = reinterpret_cast<float4*>(out + (size_t)n * DD) + dgrp;
      float4 prev = FIRST ? make_float4(0.f, 0.f, 0.f, 0.f) : *op;
      prev.x += rw * acc.x; prev.y += rw * acc.y;
      prev.z += rw * acc.z; prev.w += rw * acc.w;
      *op = prev;
    }
  }
}

// ---------------------------------------------------------------------------
// out = sigmoid(out @ Wg + bg) * out, in place. Same structure as combine.
// ---------------------------------------------------------------------------
__global__ __launch_bounds__(256) void gate_kernel(
    float* __restrict__ out, const float* __restrict__ Wg,
    const float* __restrict__ bg) {
  __shared__ float wlds[DD * DD];
  __shared__ float clds[8][DD];
  for (int i = threadIdx.x; i < DD * DD / 4; i += 256)
    reinterpret_cast<float4*>(wlds)[i] = reinterpret_cast<const float4*>(Wg)[i];
  int dgrp = threadIdx.x & 31, nl = threadIdx.x >> 5;
  float4 bv = reinterpret_cast<const float4*>(bg)[dgrp];
  int nbase = blockIdx.x * 32;
  for (int s = 0; s < 4; ++s) {
    int n0 = nbase + s * 8;
    __syncthreads();
    {
      int n = n0 + nl;
      float4 cv = make_float4(0.f, 0.f, 0.f, 0.f);
      if (n < NN) cv = reinterpret_cast<const float4*>(out + (size_t)n * DD)[dgrp];
      reinterpret_cast<float4*>(&clds[nl][0])[dgrp] = cv;
    }
    __syncthreads();
    int n = n0 + nl;
    float4 acc = bv;
#pragma unroll 8
    for (int k = 0; k < DD; ++k) {
      float c = clds[nl][k];
      float4 wv = reinterpret_cast<const float4*>(&wlds[k * DD])[dgrp];
      acc.x += c * wv.x; acc.y += c * wv.y;
      acc.z += c * wv.z; acc.w += c * wv.w;
    }
    if (n < NN) {
      float4 cv = reinterpret_cast<float4*>(&clds[nl][0])[dgrp];
      float4 res;
      res.x = cv.x / (1.f + __expf(-acc.x));
      res.y = cv.y / (1.f + __expf(-acc.y));
      res.z = cv.z / (1.f + __expf(-acc.z));
      res.w = cv.w / (1.f + __expf(-acc.w));
      reinterpret_cast<float4*>(out + (size_t)n * DD)[dgrp] = res;
    }
  }
}

// ---------------------------------------------------------------------------
extern "C" void kernel_launch(void* const* d_in, const int* in_sizes, int n_in,
                              void* d_out, int out_size, void* d_ws,
                              size_t ws_size, hipStream_t stream) {
  const float* feat = (const float*)d_in[0];
  const int* eidx   = (const int*)d_in[1];   // [4][2][800000] int32 (harness!)
  const float* ew   = (const float*)d_in[2];
  const float* Wr   = (const float*)d_in[3];
  const float* br   = (const float*)d_in[4];
  const float* Wrw  = (const float*)d_in[5];
  const float* brw  = (const float*)d_in[6];
  const float* Wg   = (const float*)d_in[7];
  const float* bg   = (const float*)d_in[8];
  float* out = (float*)d_out;

  // ws layout (27.2 MB total): H [NN*DD] | S [NR*NN] | relw [NN*NR]
  float* H = (float*)d_ws;
  float* S = H + (size_t)NN * DD;
  float* relw = S + (size_t)NR * NN;

  // zero H + S (ws is poisoned 0xAA before every timed call)
  hipMemsetAsync(d_ws, 0,
                 ((size_t)NN * DD + (size_t)NR * NN) * sizeof(float), stream);

  relw_kernel<<<(NN + 3) / 4, 256, 0, stream>>>(feat, Wrw, brw, relw);

  for (int r = 0; r < NR; ++r) {
    if (r > 0)
      hipMemsetAsync(H, 0, (size_t)NN * DD * sizeof(float), stream);
    scatter_kernel<<<(NE + 3) / 4, 256, 0, stream>>>(feat, eidx, ew, H, S, r);
    if (r == 0)
      combine_kernel<true><<<(NN + 31) / 32, 256, 0, stream>>>(
          H, S, relw, Wr, br, out, r);
    else
      combine_kernel<false><<<(NN + 31) / 32, 256, 0, stream>>>(
          H, S, relw, Wr, br, out, r);
  }

  gate_kernel<<<(NN + 31) / 32, 256, 0, stream>>>(out, Wg, bg);
}

// Round 3
// 1037.449 us; speedup vs baseline: 3.1078x; 3.1078x over previous
//
#include <hip/hip_runtime.h>

#define NN 50000
#define NR 4
#define NE 800000
#define DD 128
#define NSEG (NR * NN)                       // 200000 segments
#define SCHUNK 1024
#define NCHUNK ((NSEG + SCHUNK - 1) / SCHUNK)  // 196

// ---------------------------------------------------------------------------
// rel_w = softmax(features @ Wrw + brw)   [NN, 4]
// ---------------------------------------------------------------------------
__global__ __launch_bounds__(256) void relw_kernel(
    const float* __restrict__ feat, const float* __restrict__ Wrw,
    const float* __restrict__ brw, float* __restrict__ relw) {
  int wave = threadIdx.x >> 6, lane = threadIdx.x & 63;
  int n = blockIdx.x * 4 + wave;
  if (n >= NN) return;
  float2 f = reinterpret_cast<const float2*>(feat + (size_t)n * DD)[lane];
  float4 w0 = reinterpret_cast<const float4*>(Wrw)[2 * lane];
  float4 w1 = reinterpret_cast<const float4*>(Wrw)[2 * lane + 1];
  float a0 = f.x * w0.x + f.y * w1.x;
  float a1 = f.x * w0.y + f.y * w1.y;
  float a2 = f.x * w0.z + f.y * w1.z;
  float a3 = f.x * w0.w + f.y * w1.w;
  for (int off = 32; off; off >>= 1) {
    a0 += __shfl_xor(a0, off);
    a1 += __shfl_xor(a1, off);
    a2 += __shfl_xor(a2, off);
    a3 += __shfl_xor(a3, off);
  }
  if (lane == 0) {
    a0 += brw[0]; a1 += brw[1]; a2 += brw[2]; a3 += brw[3];
    float m = fmaxf(fmaxf(a0, a1), fmaxf(a2, a3));
    float e0 = __expf(a0 - m), e1 = __expf(a1 - m);
    float e2 = __expf(a2 - m), e3 = __expf(a3 - m);
    float inv = 1.f / (e0 + e1 + e2 + e3);
    reinterpret_cast<float4*>(relw)[n] =
        make_float4(e0 * inv, e1 * inv, e2 * inv, e3 * inv);
  }
}

// ---------------------------------------------------------------------------
// count: cnt[r*NN + dst]++ over all 3.2M edges (int atomics)
// ---------------------------------------------------------------------------
__global__ __launch_bounds__(256) void count_kernel(
    const int* __restrict__ eidx, int* __restrict__ cnt) {
  int idx = blockIdx.x * 256 + threadIdx.x;
  if (idx >= NR * NE) return;
  int r = idx / NE, e = idx - r * NE;
  int dst = eidx[(size_t)r * 2 * NE + NE + e];
  atomicAdd(&cnt[r * NN + dst], 1);
}

// ---------------------------------------------------------------------------
// 3-kernel exclusive scan over cnt[NSEG] -> off[NSEG]; off_run = copy
// ---------------------------------------------------------------------------
__global__ __launch_bounds__(256) void scan_local(
    const int* __restrict__ cnt, int* __restrict__ off,
    int* __restrict__ partial) {
  __shared__ int lds[256];
  int base = blockIdx.x * SCHUNK, t = threadIdx.x;
  int v[4], s = 0;
#pragma unroll
  for (int j = 0; j < 4; ++j) {
    int i = base + t * 4 + j;
    v[j] = (i < NSEG) ? cnt[i] : 0;
    s += v[j];
  }
  lds[t] = s;
  __syncthreads();
  for (int d = 1; d < 256; d <<= 1) {
    int x = (t >= d) ? lds[t - d] : 0;
    __syncthreads();
    lds[t] += x;
    __syncthreads();
  }
  int excl = (t == 0) ? 0 : lds[t - 1];
  if (t == 255) partial[blockIdx.x] = lds[255];
#pragma unroll
  for (int j = 0; j < 4; ++j) {
    int i = base + t * 4 + j;
    if (i < NSEG) off[i] = excl;
    excl += v[j];
  }
}

__global__ __launch_bounds__(256) void scan_partials(int* __restrict__ partial) {
  __shared__ int lds[256];
  int t = threadIdx.x;
  int v = (t < NCHUNK) ? partial[t] : 0;
  lds[t] = v;
  __syncthreads();
  for (int d = 1; d < 256; d <<= 1) {
    int x = (t >= d) ? lds[t - d] : 0;
    __syncthreads();
    lds[t] += x;
    __syncthreads();
  }
  int excl = (t == 0) ? 0 : lds[t - 1];
  if (t < NCHUNK) partial[t] = excl;
}

__global__ __launch_bounds__(256) void scan_add(
    int* __restrict__ off, const int* __restrict__ partial,
    int* __restrict__ off_run) {
  int base = blockIdx.x * SCHUNK;
  int add = partial[blockIdx.x];
  for (int j = threadIdx.x; j < SCHUNK; j += 256) {
    int i = base + j;
    if (i < NSEG) {
      int o = off[i] + add;
      off[i] = o;
      off_run[i] = o;
    }
  }
}

// ---------------------------------------------------------------------------
// place: sorted[pos] = (src, w) at pos = off_run[seg]++
// ---------------------------------------------------------------------------
__global__ __launch_bounds__(256) void place_kernel(
    const int* __restrict__ eidx, const float* __restrict__ ew,
    int* __restrict__ off_run, int* __restrict__ s_src,
    float* __restrict__ s_w) {
  int idx = blockIdx.x * 256 + threadIdx.x;
  if (idx >= NR * NE) return;
  int r = idx / NE, e = idx - r * NE;
  int src = eidx[(size_t)r * 2 * NE + e];
  int dst = eidx[(size_t)r * 2 * NE + NE + e];
  float w = ew[(size_t)r * NE + e];
  int pos = atomicAdd(&off_run[r * NN + dst], 1);
  s_src[pos] = src;
  s_w[pos] = w;
}

// ---------------------------------------------------------------------------
// gather (relation r): one wave per node; walk CSR segment, accumulate H row
// in registers (float2/lane), write once. Also emits S[r][n] = sum(w).
// ---------------------------------------------------------------------------
__global__ __launch_bounds__(256) void gather_kernel(
    const float* __restrict__ feat, const int* __restrict__ s_src,
    const float* __restrict__ s_w, const int* __restrict__ off,
    const int* __restrict__ cnt, float* __restrict__ H,
    float* __restrict__ S, int r) {
  int wave = threadIdx.x >> 6, lane = threadIdx.x & 63;
  int n = blockIdx.x * 4 + wave;
  if (n >= NN) return;
  int seg = r * NN + n;
  int start = off[seg], deg = cnt[seg];
  float ax = 0.f, ay = 0.f, bx = 0.f, by = 0.f, sw = 0.f;
  int i = 0;
  for (; i + 2 <= deg; i += 2) {
    int s0 = s_src[start + i], s1 = s_src[start + i + 1];
    float w0 = s_w[start + i], w1 = s_w[start + i + 1];
    float2 f0 = reinterpret_cast<const float2*>(feat + (size_t)s0 * DD)[lane];
    float2 f1 = reinterpret_cast<const float2*>(feat + (size_t)s1 * DD)[lane];
    ax += w0 * f0.x; ay += w0 * f0.y;
    bx += w1 * f1.x; by += w1 * f1.y;
    sw += w0 + w1;
  }
  if (i < deg) {
    int s0 = s_src[start + i];
    float w0 = s_w[start + i];
    float2 f0 = reinterpret_cast<const float2*>(feat + (size_t)s0 * DD)[lane];
    ax += w0 * f0.x; ay += w0 * f0.y;
    sw += w0;
  }
  reinterpret_cast<float2*>(H + (size_t)n * DD)[lane] =
      make_float2(ax + bx, ay + by);
  if (lane == 0) S[seg] = sw;
}

// ---------------------------------------------------------------------------
// combined += rel_w[:,r] * (H @ Wr[r] + S_r * br[r])
// ---------------------------------------------------------------------------
template <bool FIRST>
__global__ __launch_bounds__(256) void combine_kernel(
    const float* __restrict__ H, const float* __restrict__ S,
    const float* __restrict__ relw, const float* __restrict__ Wr,
    const float* __restrict__ br, float* __restrict__ out, int r) {
  __shared__ float wlds[DD * DD];
  __shared__ float hlds[8][DD];
  const float* W = Wr + (size_t)r * DD * DD;
  for (int i = threadIdx.x; i < DD * DD / 4; i += 256)
    reinterpret_cast<float4*>(wlds)[i] = reinterpret_cast<const float4*>(W)[i];
  int dgrp = threadIdx.x & 31, nl = threadIdx.x >> 5;
  float4 bv = reinterpret_cast<const float4*>(br + (size_t)r * DD)[dgrp];
  int nbase = blockIdx.x * 32;
  for (int s = 0; s < 4; ++s) {
    int n0 = nbase + s * 8;
    __syncthreads();
    {
      int n = n0 + nl;
      float4 hv = make_float4(0.f, 0.f, 0.f, 0.f);
      if (n < NN) hv = reinterpret_cast<const float4*>(H + (size_t)n * DD)[dgrp];
      reinterpret_cast<float4*>(&hlds[nl][0])[dgrp] = hv;
    }
    __syncthreads();
    int n = n0 + nl;
    float sv = 0.f, rw = 0.f;
    if (n < NN) {
      sv = S[(size_t)r * NN + n];
      rw = relw[n * 4 + r];
    }
    float4 acc = make_float4(sv * bv.x, sv * bv.y, sv * bv.z, sv * bv.w);
#pragma unroll 8
    for (int k = 0; k < DD; ++k) {
      float h = hlds[nl][k];
      float4 wv = reinterpret_cast<const float4*>(&wlds[k * DD])[dgrp];
      acc.x += h * wv.x; acc.y += h * wv.y;
      acc.z += h * wv.z; acc.w += h * wv.w;
    }
    if (n < NN) {
      float4* op = reinterpret_cast<float4*>(out + (size_t)n * DD) + dgrp;
      float4 prev = FIRST ? make_float4(0.f, 0.f, 0.f, 0.f) : *op;
      prev.x += rw * acc.x; prev.y += rw * acc.y;
      prev.z += rw * acc.z; prev.w += rw * acc.w;
      *op = prev;
    }
  }
}

// ---------------------------------------------------------------------------
// out = sigmoid(out @ Wg + bg) * out, in place
// ---------------------------------------------------------------------------
__global__ __launch_bounds__(256) void gate_kernel(
    float* __restrict__ out, const float* __restrict__ Wg,
    const float* __restrict__ bg) {
  __shared__ float wlds[DD * DD];
  __shared__ float clds[8][DD];
  for (int i = threadIdx.x; i < DD * DD / 4; i += 256)
    reinterpret_cast<float4*>(wlds)[i] = reinterpret_cast<const float4*>(Wg)[i];
  int dgrp = threadIdx.x & 31, nl = threadIdx.x >> 5;
  float4 bv = reinterpret_cast<const float4*>(bg)[dgrp];
  int nbase = blockIdx.x * 32;
  for (int s = 0; s < 4; ++s) {
    int n0 = nbase + s * 8;
    __syncthreads();
    {
      int n = n0 + nl;
      float4 cv = make_float4(0.f, 0.f, 0.f, 0.f);
      if (n < NN) cv = reinterpret_cast<const float4*>(out + (size_t)n * DD)[dgrp];
      reinterpret_cast<float4*>(&clds[nl][0])[dgrp] = cv;
    }
    __syncthreads();
    int n = n0 + nl;
    float4 acc = bv;
#pragma unroll 8
    for (int k = 0; k < DD; ++k) {
      float c = clds[nl][k];
      float4 wv = reinterpret_cast<const float4*>(&wlds[k * DD])[dgrp];
      acc.x += c * wv.x; acc.y += c * wv.y;
      acc.z += c * wv.z; acc.w += c * wv.w;
    }
    if (n < NN) {
      float4 cv = reinterpret_cast<float4*>(&clds[nl][0])[dgrp];
      float4 res;
      res.x = cv.x / (1.f + __expf(-acc.x));
      res.y = cv.y / (1.f + __expf(-acc.y));
      res.z = cv.z / (1.f + __expf(-acc.z));
      res.w = cv.w / (1.f + __expf(-acc.w));
      reinterpret_cast<float4*>(out + (size_t)n * DD)[dgrp] = res;
    }
  }
}

// ---------------------------------------------------------------------------
extern "C" void kernel_launch(void* const* d_in, const int* in_sizes, int n_in,
                              void* d_out, int out_size, void* d_ws,
                              size_t ws_size, hipStream_t stream) {
  const float* feat = (const float*)d_in[0];
  const int* eidx   = (const int*)d_in[1];   // [4][2][800000] int32
  const float* ew   = (const float*)d_in[2];
  const float* Wr   = (const float*)d_in[3];
  const float* br   = (const float*)d_in[4];
  const float* Wrw  = (const float*)d_in[5];
  const float* brw  = (const float*)d_in[6];
  const float* Wg   = (const float*)d_in[7];
  const float* bg   = (const float*)d_in[8];
  float* out = (float*)d_out;

  // ws layout (~55.2 MB):
  char* p = (char*)d_ws;
  float* H      = (float*)p;  p += (size_t)NN * DD * 4;        // 25.6 MB
  int*   s_src  = (int*)p;    p += (size_t)NR * NE * 4;        // 12.8 MB
  float* s_w    = (float*)p;  p += (size_t)NR * NE * 4;        // 12.8 MB
  int*   cnt    = (int*)p;    p += (size_t)NSEG * 4;           // 0.8 MB
  int*   off    = (int*)p;    p += (size_t)NSEG * 4;
  int*   offrun = (int*)p;    p += (size_t)NSEG * 4;
  int*   part   = (int*)p;    p += 1024;
  float* S      = (float*)p;  p += (size_t)NSEG * 4;
  float* relw   = (float*)p;  p += (size_t)NN * NR * 4;

  // only cnt needs zeroing
  hipMemsetAsync(cnt, 0, (size_t)NSEG * 4, stream);

  relw_kernel<<<(NN + 3) / 4, 256, 0, stream>>>(feat, Wrw, brw, relw);

  count_kernel<<<(NR * NE + 255) / 256, 256, 0, stream>>>(eidx, cnt);
  scan_local<<<NCHUNK, 256, 0, stream>>>(cnt, off, part);
  scan_partials<<<1, 256, 0, stream>>>(part);
  scan_add<<<NCHUNK, 256, 0, stream>>>(off, part, offrun);
  place_kernel<<<(NR * NE + 255) / 256, 256, 0, stream>>>(eidx, ew, offrun,
                                                          s_src, s_w);

  for (int r = 0; r < NR; ++r) {
    gather_kernel<<<(NN + 3) / 4, 256, 0, stream>>>(feat, s_src, s_w, off,
                                                    cnt, H, S, r);
    if (r == 0)
      combine_kernel<true><<<(NN + 31) / 32, 256, 0, stream>>>(
          H, S, relw, Wr, br, out, r);
    else
      combine_kernel<false><<<(NN + 31) / 32, 256, 0, stream>>>(
          H, S, relw, Wr, br, out, r);
  }

  gate_kernel<<<(NN + 31) / 32, 256, 0, stream>>>(out, Wg, bg);
}